// Round 2
// baseline (9701.986 us; speedup 1.0000x reference)
//
#include <hip/hip_runtime.h>
#include <math.h>

// FNO3D encoder: B=4, CIN=1, 64^3, W=32 ch, L=6 layers, M=32 modes.
// h lives in d_out (fp32 [4][32][64][64][64]); spectral accumulator s in d_ws.

#define BB 4
#define CC 32
#define NN 64
#define MM 32
#define NSITE 8          // perpendicular sites per block
#define STH 512          // spectral block threads

// ---------------- lift: [x,gx,gy,gz] -> 16 (gelu) -> 32 ----------------
__global__ __launch_bounds__(256) void lift_kernel(
    const float* __restrict__ x,
    const float* __restrict__ lw1, const float* __restrict__ lb1,
    const float* __restrict__ lw2, const float* __restrict__ lb2,
    float* __restrict__ h)
{
    __shared__ float w1[64], b1s[16], w2[512], b2s[32];
    int tid = threadIdx.x;
    if (tid < 64) w1[tid] = lw1[tid];
    if (tid < 16) b1s[tid] = lb1[tid];
    for (int i = tid; i < 512; i += 256) w2[i] = lw2[i];
    if (tid < 32) b2s[tid] = lb2[tid];
    __syncthreads();

    int v = blockIdx.x * 256 + tid;          // 0 .. 1M-1
    int b = v >> 18;
    int vox = v & 262143;
    float feat0 = x[b * 262144 + vox];
    float feat1 = (float)(vox >> 12)        * (1.0f / 63.0f);
    float feat2 = (float)((vox >> 6) & 63)  * (1.0f / 63.0f);
    float feat3 = (float)(vox & 63)         * (1.0f / 63.0f);

    float t1[16];
#pragma unroll
    for (int o = 0; o < 16; ++o) {
        float a = b1s[o];
        a = fmaf(w1[o * 4 + 0], feat0, a);
        a = fmaf(w1[o * 4 + 1], feat1, a);
        a = fmaf(w1[o * 4 + 2], feat2, a);
        a = fmaf(w1[o * 4 + 3], feat3, a);
        t1[o] = 0.5f * a * (1.0f + erff(a * 0.70710678118654752f));
    }
    int base = b * CC * 262144 + vox;
#pragma unroll
    for (int c = 0; c < 32; ++c) {
        float a = b2s[c];
#pragma unroll
        for (int o = 0; o < 16; ++o) a = fmaf(w2[c * 16 + o], t1[o], a);
        h[base + c * 262144] = a;
    }
}

// ---------------- fused spectral conv along one axis ----------------
// AXIS: 2 = z (stride 1), 1 = y (stride 64), 0 = x (stride 4096)
// LDS float layout (34176 floats = 133.5 KB):
//  region A @0      : xbuf  [256 lines][66]          (16896 f)  -> later mspec float2 [256][33]
//  region B @16896  : spec  float2 [8 s][32 c][32 m] (16384 f)  -> later ybuf float [256][67] (17152 f)
//  roots   @34048   : float2[64]                     (128 f)
template <int AXIS, bool ACCUM>
__global__ __launch_bounds__(STH) void spectral_kernel(
    const float* __restrict__ h, float* __restrict__ sout,
    const float2* __restrict__ w)
{
    __shared__ float lds[34176];
    float*  xm    = lds;
    float2* mspec = (float2*)lds;
    float2* spec  = (float2*)(lds + 16896);
    float*  ybuf  = lds + 16896;
    float2* roots = (float2*)(lds + 34048);

    const int tid = threadIdx.x;
    const int site0 = blockIdx.x * NSITE;        // 16384 sites total
    const int b  = site0 >> 12;
    const int q0 = site0 & 4095;

    if (tid < 64) {
        float ss, sc;
        sincosf((float)tid * (6.283185307179586f / 64.0f), &ss, &sc);
        roots[tid] = make_float2(sc, ss);
    }
    __syncthreads();

    // ---- load lines into LDS: xbuf[line = c*8+s][t] ----
#pragma unroll
    for (int k = 0; k < 32; ++k) {
        int e = tid + k * STH;
        int c, s, t;
        if (AXIS == 2) { t = e & 63; s = (e >> 6) & 7; c = e >> 9; }
        else           { s = e & 7;  t = (e >> 3) & 63; c = e >> 9; }
        int q = q0 + s;
        int addr;
        if (AXIS == 2)      addr = (b * CC + c) * 262144 + q * 64 + t;
        else if (AXIS == 1) addr = (b * CC + c) * 262144 + (q >> 6) * 4096 + t * 64 + (q & 63);
        else                addr = (b * CC + c) * 262144 + t * 4096 + (q >> 6) * 64 + (q & 63);
        xm[(c * NSITE + s) * 66 + t] = h[addr];
    }
    __syncthreads();

    // ---- forward DFT: spec[s][c][m] = (1/8) sum_t x[t] e^{-2pi i m t /64}, m<32 ----
    {
        const int mt = tid & 7;     // mode tile (4 modes)
        const int lt = tid >> 3;    // line tile (4 lines), 0..63
        const int m0 = mt * 4;
        float ar[4][4], ai[4][4];
#pragma unroll
        for (int j = 0; j < 4; ++j)
#pragma unroll
            for (int i = 0; i < 4; ++i) { ar[j][i] = 0.0f; ai[j][i] = 0.0f; }
        int idx0 = 0, idx1 = 0, idx2 = 0, idx3 = 0;
        for (int t = 0; t < 64; ++t) {
            float xv[4];
#pragma unroll
            for (int j = 0; j < 4; ++j) xv[j] = xm[(lt * 4 + j) * 66 + t];
            float2 r0 = roots[idx0], r1 = roots[idx1], r2 = roots[idx2], r3 = roots[idx3];
            idx0 = (idx0 + m0 + 0) & 63;
            idx1 = (idx1 + m0 + 1) & 63;
            idx2 = (idx2 + m0 + 2) & 63;
            idx3 = (idx3 + m0 + 3) & 63;
#pragma unroll
            for (int j = 0; j < 4; ++j) {
                ar[j][0] = fmaf(xv[j], r0.x, ar[j][0]); ai[j][0] = fmaf(-xv[j], r0.y, ai[j][0]);
                ar[j][1] = fmaf(xv[j], r1.x, ar[j][1]); ai[j][1] = fmaf(-xv[j], r1.y, ai[j][1]);
                ar[j][2] = fmaf(xv[j], r2.x, ar[j][2]); ai[j][2] = fmaf(-xv[j], r2.y, ai[j][2]);
                ar[j][3] = fmaf(xv[j], r3.x, ar[j][3]); ai[j][3] = fmaf(-xv[j], r3.y, ai[j][3]);
            }
        }
#pragma unroll
        for (int j = 0; j < 4; ++j) {
            int line = lt * 4 + j;
            int c = line >> 3, s = line & 7;
#pragma unroll
            for (int i = 0; i < 4; ++i)
                spec[(s * CC + c) * MM + m0 + i] =
                    make_float2(ar[j][i] * 0.125f, ai[j][i] * 0.125f);
        }
    }
    __syncthreads();

    // ---- mode mix: mspec[o*8+s][m] = sum_i spec[s][i][m] * w[i][o][m] ----
    {
        const int m  = tid & 31;
        const int st = (tid >> 5) & 1;   // site tile (4 sites)
        const int ot = tid >> 6;         // out tile (4 outs), 0..7
        float ar[4][4], ai[4][4];
#pragma unroll
        for (int js = 0; js < 4; ++js)
#pragma unroll
            for (int jo = 0; jo < 4; ++jo) { ar[js][jo] = 0.0f; ai[js][jo] = 0.0f; }
        for (int i = 0; i < CC; ++i) {
            float2 sv[4];
#pragma unroll
            for (int js = 0; js < 4; ++js) sv[js] = spec[((st * 4 + js) * CC + i) * MM + m];
#pragma unroll
            for (int jo = 0; jo < 4; ++jo) {
                float2 wv = w[(i * CC + ot * 4 + jo) * MM + m];
#pragma unroll
                for (int js = 0; js < 4; ++js) {
                    ar[js][jo] = fmaf(sv[js].x, wv.x, fmaf(-sv[js].y, wv.y, ar[js][jo]));
                    ai[js][jo] = fmaf(sv[js].x, wv.y, fmaf( sv[js].y, wv.x, ai[js][jo]));
                }
            }
        }
        __syncthreads();   // order: all spec reads (region B) complete before ybuf (region B) is written in the inverse-DFT phase
#pragma unroll
        for (int js = 0; js < 4; ++js) {
            int s = st * 4 + js;
#pragma unroll
            for (int jo = 0; jo < 4; ++jo) {
                int o = ot * 4 + jo;
                mspec[(o * NSITE + s) * 33 + m] = make_float2(ar[js][jo], ai[js][jo]);
            }
        }
    }
    __syncthreads();

    // ---- inverse DFT: y[t] = 0.125*(m0r + 2*sum_{m=1}^{31}(re*cos - im*sin)) ----
    {
        const int tt = tid & 7;     // t tile (8 t)
        const int lt = tid >> 3;    // line tile (4 lines), 0..63
        float acc[4][8];
#pragma unroll
        for (int j = 0; j < 4; ++j) {
            float m0r = mspec[(lt * 4 + j) * 33].x;
#pragma unroll
            for (int u = 0; u < 8; ++u) acc[j][u] = 0.5f * m0r;
        }
        for (int m = 1; m < 32; ++m) {
            float2 sv[4];
#pragma unroll
            for (int j = 0; j < 4; ++j) sv[j] = mspec[(lt * 4 + j) * 33 + m];
            int idx = (m * tt * 8) & 63;
#pragma unroll
            for (int u = 0; u < 8; ++u) {
                float2 rt = roots[idx];
                idx = (idx + m) & 63;
#pragma unroll
                for (int j = 0; j < 4; ++j) {
                    acc[j][u] = fmaf(sv[j].x, rt.x, acc[j][u]);
                    acc[j][u] = fmaf(-sv[j].y, rt.y, acc[j][u]);
                }
            }
        }
        // ybuf (region B) does not alias mspec (region A); spec reads were barriered above.
#pragma unroll
        for (int j = 0; j < 4; ++j)
#pragma unroll
            for (int u = 0; u < 8; ++u)
                ybuf[(lt * 4 + j) * 67 + tt * 8 + u] = acc[j][u] * 0.25f;
    }
    __syncthreads();

    // ---- store / accumulate to s ----
#pragma unroll
    for (int k = 0; k < 32; ++k) {
        int e = tid + k * STH;
        int o, s, t;
        if (AXIS == 2) { t = e & 63; s = (e >> 6) & 7; o = e >> 9; }
        else           { s = e & 7;  t = (e >> 3) & 63; o = e >> 9; }
        int q = q0 + s;
        int addr;
        if (AXIS == 2)      addr = (b * CC + o) * 262144 + q * 64 + t;
        else if (AXIS == 1) addr = (b * CC + o) * 262144 + (q >> 6) * 4096 + t * 64 + (q & 63);
        else                addr = (b * CC + o) * 262144 + t * 4096 + (q >> 6) * 64 + (q & 63);
        float v = ybuf[(o * NSITE + s) * 67 + t];
        if (ACCUM) sout[addr] += v;
        else       sout[addr] = v;
    }
}

// ---------------- per-layer MLP: h = (mw2 @ gelu(mw1 @ s + mb1) + mb2) + h ----------------
__global__ __launch_bounds__(256) void mlp_kernel(
    const float* __restrict__ sin_, float* hio,
    const float* __restrict__ mw1, const float* __restrict__ mb1,
    const float* __restrict__ mw2, const float* __restrict__ mb2)
{
    __shared__ float w1[2048], bb1[64], w2[2048], bb2[32];
    int tid = threadIdx.x;
    for (int i = tid; i < 2048; i += 256) { w1[i] = mw1[i]; w2[i] = mw2[i]; }
    if (tid < 64) bb1[tid] = mb1[tid];
    if (tid < 32) bb2[tid] = mb2[tid];
    __syncthreads();

    int v = blockIdx.x * 256 + tid;
    int b = v >> 18;
    int vox = v & 262143;
    int base = b * CC * 262144 + vox;

    float sv[32];
#pragma unroll
    for (int i = 0; i < 32; ++i) sv[i] = sin_[base + i * 262144];

    float t1[64];
#pragma unroll
    for (int o = 0; o < 64; ++o) {
        float a = bb1[o];
#pragma unroll
        for (int i = 0; i < 32; ++i) a = fmaf(w1[o * 32 + i], sv[i], a);
        t1[o] = 0.5f * a * (1.0f + erff(a * 0.70710678118654752f));
    }
#pragma unroll
    for (int c = 0; c < 32; ++c) {
        float a = bb2[c];
#pragma unroll
        for (int o = 0; o < 64; ++o) a = fmaf(w2[c * 64 + o], t1[o], a);
        hio[base + c * 262144] += a;
    }
}

extern "C" void kernel_launch(void* const* d_in, const int* in_sizes, int n_in,
                              void* d_out, int out_size, void* d_ws, size_t ws_size,
                              hipStream_t stream) {
    const float* x   = (const float*)d_in[0];
    const float* lw1 = (const float*)d_in[1];
    const float* lb1 = (const float*)d_in[2];
    const float* lw2 = (const float*)d_in[3];
    const float* lb2 = (const float*)d_in[4];
    const float* wx  = (const float*)d_in[5];
    const float* wy  = (const float*)d_in[6];
    const float* wz  = (const float*)d_in[7];
    const float* mw1 = (const float*)d_in[8];
    const float* mb1 = (const float*)d_in[9];
    const float* mw2 = (const float*)d_in[10];
    const float* mb2 = (const float*)d_in[11];

    float* h = (float*)d_out;   // h resident in d_out
    float* s = (float*)d_ws;    // spectral accumulator (128 MB)

    lift_kernel<<<4096, 256, 0, stream>>>(x, lw1, lb1, lw2, lb2, h);

    for (int l = 0; l < 6; ++l) {
        const float2* wxl = (const float2*)wx + l * 32768;
        const float2* wyl = (const float2*)wy + l * 32768;
        const float2* wzl = (const float2*)wz + l * 32768;
        spectral_kernel<2, false><<<2048, STH, 0, stream>>>(h, s, wzl);
        spectral_kernel<1, true ><<<2048, STH, 0, stream>>>(h, s, wyl);
        spectral_kernel<0, true ><<<2048, STH, 0, stream>>>(h, s, wxl);
        mlp_kernel<<<4096, 256, 0, stream>>>(s, h,
            mw1 + l * 2048, mb1 + l * 64, mw2 + l * 2048, mb2 + l * 32);
    }
}